// Round 9
// baseline (150.064 us; speedup 1.0000x reference)
//
#include <hip/hip_runtime.h>

// RoIAlign (max-pool variant) for MI355X — fp32, R9.
//  K1: tiled transpose (B,C,HW)->(B,HW,C), float4 on BOTH global sides
//      (b32 LDS, 65-pad: uniform 2-way bank alias = free on gfx950).
//  K2: grid (N,2) = (roi, channel-half), 128 ch/block, lane=4ch (float4),
//      half-waves = bins (R8 structure, contiguous 25KB output span per
//      block). NEW: pair-loop unrolled x2 — 32 float4 loads (4 bins) in
//      flight before the first compute; __launch_bounds__(256,4) caps
//      VGPR<=128 so occupancy stays >=4 blocks/CU. Attacks the measured
//      ~30%-VALUBusy latency-exposure duty cycle.
// Numerics identical to R2-R8 (same per-component op order) — absmax 0.0156.

namespace {

constexpr int B_ = 4, C_ = 256, H_ = 50, W_ = 50;
constexpr int HW = H_ * W_;                     // 2500
constexpr int HO = 7, WO = 7, NBIN = HO * WO;   // 49
constexpr int OUT_PER_ROI = C_ * NBIN;          // 12544
constexpr int CPB = 128;                        // channels per block
constexpr int COLS = CPB / 4;                   // 32 float4 columns
constexpr int LDs = 132;                        // stage leading dim (132%32=4, mult of 4)
constexpr float RATIO = 1.0f / 32.0f;

// ---------------- K1: tiled transpose, float4 both sides ----------------
__global__ __launch_bounds__(256) void transpose_tiled(
    const float* __restrict__ f, float* __restrict__ ft)
{
    __shared__ float tile[64][65];               // [ch][hw], pad->2-way alias (free)
    const int bt   = blockIdx.x;
    const int hw_t = bt % 40;
    const int c_t  = (bt / 40) % 4;
    const int b    = bt / 160;
    const int hw0 = hw_t * 64, c0 = c_t * 64;
    const int x4 = threadIdx.x & 15;             // float4 slot
    const int cr = threadIdx.x >> 4;             // 0..15

#pragma unroll
    for (int p = 0; p < 4; ++p) {                // load: rows = channels
        const int ch = p * 16 + cr;              // 0..63
        const int hw = hw0 + x4 * 4;
        if (hw < HW) {                           // HW%4==0: full float4 or none
            const float4 v = *(const float4*)&f[((size_t)(b * C_ + c0 + ch)) * HW + hw];
            tile[ch][x4 * 4 + 0] = v.x;
            tile[ch][x4 * 4 + 1] = v.y;
            tile[ch][x4 * 4 + 2] = v.z;
            tile[ch][x4 * 4 + 3] = v.w;
        }
    }
    __syncthreads();
#pragma unroll
    for (int p = 0; p < 4; ++p) {                // store: rows = hw, float4 of ch
        const int hwr = p * 16 + cr;
        const int hw  = hw0 + hwr;
        if (hw < HW) {
            float4 v;
            v.x = tile[x4 * 4 + 0][hwr];
            v.y = tile[x4 * 4 + 1][hwr];
            v.z = tile[x4 * 4 + 2][hwr];
            v.w = tile[x4 * 4 + 3][hwr];
            *(float4*)&ft[((size_t)b * HW + hw) * C_ + c0 + x4 * 4] = v;
        }
    }
}

// ---------------- K2: main ----------------
__global__ __launch_bounds__(256, 4) void roialign_main(
    const float* __restrict__ ft,       // (B,HW,C)
    const float* __restrict__ rois,
    float* __restrict__ out)
{
    __shared__ float stage[NBIN * LDs];                  // 25872 B
    __shared__ __align__(16) float    wts[NBIN][8];      // wxh0,wxh1,wxl0,wxl1,wyb0,wyb1,wyt0,wyt1 (x valid)
    __shared__ __align__(16) unsigned offs[NBIN][8];     // per sample s: [2s]=tl|tr<<16, [2s+1]=bl|br<<16

    const int n    = blockIdx.x;
    const int half = blockIdx.y;
    const int tid  = threadIdx.x;
    const int wave = tid >> 6;
    const int lane = tid & 63;
    const int col  = lane & 31;                          // float4 column 0..31
    const int sub  = lane >> 5;                          // which bin of the pair
    const float fW = (float)W_, fH = (float)H_;

    // ---- Phase 1: per-bin geometry (threads 0..48) ----
    if (tid < NBIN) {
        const int ii = tid / WO, jj = tid % WO;
        const float* r = rois + n * 5;
        const float bx1 = fminf(fmaxf(r[1] * RATIO, 0.0f), fW);
        const float by1 = fminf(fmaxf(r[2] * RATIO, 0.0f), fH);
        const float bx2 = fminf(fmaxf(r[3] * RATIO, 0.0f), fW);
        const float by2 = fminf(fmaxf(r[4] * RATIO, 0.0f), fH);
        const bool roi_valid = (bx2 - bx1 > 0.0f) && (by2 - by1 > 0.0f);
        const float bin_w = (bx2 - bx1) * (1.0f / (float)WO);
        const float bin_h = (by2 - by1) * (1.0f / (float)HO);

        const float x1u = bx1 + (float)jj * bin_w;
        const float x1b = fminf(fmaxf(x1u, 0.0f), fW);
        const float x2b = fminf(fmaxf(x1u + bin_w, 0.0f), fW);
        const float y1u = by1 + (float)ii * bin_h;
        const float y1b = fminf(fmaxf(y1u, 0.0f), fH);
        const float y2b = fminf(fmaxf(y1u + bin_h, 0.0f), fH);
        const float vf = (roi_valid && (y2b > y1b) && (x2b > x1b)) ? 1.0f : 0.0f;

        int xl[2], xh[2], yl[2], yh[2];
#pragma unroll
        for (int s = 0; s < 2; ++s) {
            const float px = x1b + ((float)s + 0.5f) * (bin_w * 0.5f);
            int l = (int)floorf(px);
            l = min(max(l, 0), W_ - 1);
            const int h = min(l + 1, W_ - 1);
            xl[s] = l; xh[s] = h;
            wts[tid][0 + s] = vf * (px - (float)l);      // wxh[s]
            wts[tid][2 + s] = vf * ((float)h - px);      // wxl[s]

            const float py = y1b + ((float)s + 0.5f) * (bin_h * 0.5f);
            int t = (int)floorf(py);
            t = min(max(t, 0), H_ - 1);
            const int u = min(t + 1, H_ - 1);
            yl[s] = t; yh[s] = u;
            wts[tid][4 + s] = py - (float)t;             // wyb[s]
            wts[tid][6 + s] = (float)u - py;             // wyt[s]
        }
#pragma unroll
        for (int sy = 0; sy < 2; ++sy) {
#pragma unroll
            for (int sx = 0; sx < 2; ++sx) {
                const int s = sy * 2 + sx;
                const unsigned tl = (unsigned)(yl[sy] * W_ + xl[sx]);
                const unsigned tr = (unsigned)(yl[sy] * W_ + xh[sx]);
                const unsigned bl = (unsigned)(yh[sy] * W_ + xl[sx]);
                const unsigned br = (unsigned)(yh[sy] * W_ + xh[sx]);
                offs[tid][s * 2 + 0] = tl | (tr << 16);
                offs[tid][s * 2 + 1] = bl | (br << 16);
            }
        }
    }
    __syncthreads();

    // ---- Phase 2: half-waves = bins; x2-unrolled pair loop, 32 loads in flight ----
    int b = (int)rois[n * 5];
    b = min(max(b, 0), B_ - 1);
    const float4* pb = (const float4*)(ft + (size_t)b * HW * C_) + half * COLS + col;

    struct Meta { float4 wa, wb; uint4 oa, ob; int bin; };
    auto read_meta = [&](int i0) -> Meta {
        Meta m;
        m.bin = i0 + sub;
        const int bc = min(m.bin, NBIN - 1);
        m.wa = *(const float4*)wts[bc];
        m.wb = *(const float4*)(wts[bc] + 4);
        m.oa = *(const uint4*)&offs[bc][0];
        m.ob = *(const uint4*)&offs[bc][4];
        return m;
    };
    auto issue_loads = [&](const Meta& mt, float4 L[16]) {
        const unsigned o[8] = { mt.oa.x, mt.oa.y, mt.oa.z, mt.oa.w,
                                mt.ob.x, mt.ob.y, mt.ob.z, mt.ob.w };
#pragma unroll
        for (int s = 0; s < 4; ++s) {
            const unsigned pt = o[2 * s], pbm = o[2 * s + 1];
            L[4 * s + 0] = pb[(int)(pt  & 0xffffu) << 6];   // tl
            L[4 * s + 1] = pb[(int)(pt  >> 16)     << 6];   // tr
            L[4 * s + 2] = pb[(int)(pbm & 0xffffu) << 6];   // bl
            L[4 * s + 3] = pb[(int)(pbm >> 16)     << 6];   // br
        }
    };
    auto compute_stage = [&](const Meta& mt, const float4 L[16]) {
        float4 s4[4];
#pragma unroll
        for (int s = 0; s < 4; ++s) {
            const int sx = s & 1, sy = s >> 1;
            const float wxh = sx ? mt.wa.y : mt.wa.x;
            const float wxl = sx ? mt.wa.w : mt.wa.z;
            const float wyb = sy ? mt.wb.y : mt.wb.x;
            const float wyt = sy ? mt.wb.w : mt.wb.z;
            const float4 tl = L[4 * s + 0], tr = L[4 * s + 1];
            const float4 bl = L[4 * s + 2], br = L[4 * s + 3];
            float4 o;
            o.x = wyb * (wxh * br.x + wxl * bl.x) + wyt * (wxh * tr.x + wxl * tl.x);
            o.y = wyb * (wxh * br.y + wxl * bl.y) + wyt * (wxh * tr.y + wxl * tl.y);
            o.z = wyb * (wxh * br.z + wxl * bl.z) + wyt * (wxh * tr.z + wxl * tl.z);
            o.w = wyb * (wxh * br.w + wxl * bl.w) + wyt * (wxh * tr.w + wxl * tl.w);
            s4[s] = o;
        }
        float4 m;
        m.x = fmaxf(fmaxf(s4[0].x, s4[1].x), fmaxf(s4[2].x, s4[3].x));
        m.y = fmaxf(fmaxf(s4[0].y, s4[1].y), fmaxf(s4[2].y, s4[3].y));
        m.z = fmaxf(fmaxf(s4[0].z, s4[1].z), fmaxf(s4[2].z, s4[3].z));
        m.w = fmaxf(fmaxf(s4[0].w, s4[1].w), fmaxf(s4[2].w, s4[3].w));
        if (mt.bin < NBIN)
            *(float4*)&stage[mt.bin * LDs + 4 * col] = m;
    };

    for (int i0 = wave * 2; i0 < NBIN; i0 += 16) {
        const int iB = i0 + 8;
        const bool hasB = (iB < NBIN);           // wave-uniform
        Meta mA = read_meta(i0);
        float4 LA[16];
        issue_loads(mA, LA);
        Meta mB;
        float4 LB[16];
        if (hasB) { mB = read_meta(iB); issue_loads(mB, LB); }
        compute_stage(mA, LA);
        if (hasB) compute_stage(mB, LB);
    }
    __syncthreads();

    // ---- Phase 3: one contiguous 25088B span per block ----
    float* outn = out + (size_t)n * OUT_PER_ROI + half * (CPB * NBIN);
    for (int k = tid; k < CPB * NBIN; k += 256) {
        const int ch = k / NBIN;                         // magic mul
        const int bi = k - ch * NBIN;
        outn[k] = stage[bi * LDs + ch];
    }
}

} // namespace

extern "C" void kernel_launch(void* const* d_in, const int* in_sizes, int n_in,
                              void* d_out, int out_size, void* d_ws, size_t ws_size,
                              hipStream_t stream)
{
    const float* feats = (const float*)d_in[0];
    const float* rois  = (const float*)d_in[1];
    float* out = (float*)d_out;
    const int N = in_sizes[1] / 5;                    // 1024
    float* ft = (float*)d_ws;                         // 10.24 MB

    hipLaunchKernelGGL(transpose_tiled, dim3(B_ * 4 * 40), dim3(256), 0, stream,
                       feats, ft);
    hipLaunchKernelGGL(roialign_main, dim3(N, 2), dim3(256), 0, stream,
                       ft, rois, out);
}

// Round 10
// 103.756 us; speedup vs baseline: 1.4463x; 1.4463x over previous
//
#include <hip/hip_runtime.h>

// RoIAlign (max-pool variant) for MI355X — fp32, R10.
//  = R8 main kernel (verified ~31 µs, no spill) + R9 float4 transpose.
//  K1: tiled transpose (B,C,HW)->(B,HW,C), float4 on BOTH global sides.
//  K2: grid (N,2) = (roi, channel-half). 128 ch/block; lane = 4 ch (float4);
//      half-waves = bins (2 bins per wave instruction). Contiguous 25 KB
//      output span per block (never split the inner output run — R7 lesson).
//      NO deep unroll: R9 showed 32 float4 temporaries spill at VGPR=64 and
//      scratch traffic quintuples WRITE_SIZE.
// Numerics identical to R2-R9 (same per-component op order) — absmax 0.0156.

namespace {

constexpr int B_ = 4, C_ = 256, H_ = 50, W_ = 50;
constexpr int HW = H_ * W_;                     // 2500
constexpr int HO = 7, WO = 7, NBIN = HO * WO;   // 49
constexpr int OUT_PER_ROI = C_ * NBIN;          // 12544
constexpr int CPB = 128;                        // channels per block
constexpr int COLS = CPB / 4;                   // 32 float4 columns
constexpr int LDs = 132;                        // stage leading dim (mult of 4)
constexpr float RATIO = 1.0f / 32.0f;

// ---------------- K1: tiled transpose, float4 both sides ----------------
__global__ __launch_bounds__(256) void transpose_tiled(
    const float* __restrict__ f, float* __restrict__ ft)
{
    __shared__ float tile[64][65];               // [ch][hw]
    const int bt   = blockIdx.x;
    const int hw_t = bt % 40;
    const int c_t  = (bt / 40) % 4;
    const int b    = bt / 160;
    const int hw0 = hw_t * 64, c0 = c_t * 64;
    const int x4 = threadIdx.x & 15;             // float4 slot
    const int cr = threadIdx.x >> 4;             // 0..15

#pragma unroll
    for (int p = 0; p < 4; ++p) {                // load: rows = channels
        const int ch = p * 16 + cr;              // 0..63
        const int hw = hw0 + x4 * 4;
        if (hw < HW) {                           // HW%4==0: full float4 or none
            const float4 v = *(const float4*)&f[((size_t)(b * C_ + c0 + ch)) * HW + hw];
            tile[ch][x4 * 4 + 0] = v.x;
            tile[ch][x4 * 4 + 1] = v.y;
            tile[ch][x4 * 4 + 2] = v.z;
            tile[ch][x4 * 4 + 3] = v.w;
        }
    }
    __syncthreads();
#pragma unroll
    for (int p = 0; p < 4; ++p) {                // store: rows = hw, float4 of ch
        const int hwr = p * 16 + cr;
        const int hw  = hw0 + hwr;
        if (hw < HW) {
            float4 v;
            v.x = tile[x4 * 4 + 0][hwr];
            v.y = tile[x4 * 4 + 1][hwr];
            v.z = tile[x4 * 4 + 2][hwr];
            v.w = tile[x4 * 4 + 3][hwr];
            *(float4*)&ft[((size_t)b * HW + hw) * C_ + c0 + x4 * 4] = v;
        }
    }
}

// ---------------- K2: main (R8 verbatim) ----------------
__global__ __launch_bounds__(256, 5) void roialign_main(
    const float* __restrict__ ft,       // (B,HW,C)
    const float* __restrict__ rois,
    float* __restrict__ out)
{
    __shared__ float stage[NBIN * LDs];                  // 25872 B
    __shared__ __align__(16) float    wts[NBIN][8];      // wxh0,wxh1,wxl0,wxl1,wyb0,wyb1,wyt0,wyt1 (x valid)
    __shared__ __align__(16) unsigned offs[NBIN][8];     // per sample s: [2s]=tl|tr<<16, [2s+1]=bl|br<<16

    const int n    = blockIdx.x;
    const int half = blockIdx.y;
    const int tid  = threadIdx.x;
    const int wave = tid >> 6;
    const int lane = tid & 63;
    const int col  = lane & 31;                          // float4 column 0..31
    const int sub  = lane >> 5;                          // which bin of the pair
    const float fW = (float)W_, fH = (float)H_;

    // ---- Phase 1: per-bin geometry (threads 0..48) ----
    if (tid < NBIN) {
        const int ii = tid / WO, jj = tid % WO;
        const float* r = rois + n * 5;
        const float bx1 = fminf(fmaxf(r[1] * RATIO, 0.0f), fW);
        const float by1 = fminf(fmaxf(r[2] * RATIO, 0.0f), fH);
        const float bx2 = fminf(fmaxf(r[3] * RATIO, 0.0f), fW);
        const float by2 = fminf(fmaxf(r[4] * RATIO, 0.0f), fH);
        const bool roi_valid = (bx2 - bx1 > 0.0f) && (by2 - by1 > 0.0f);
        const float bin_w = (bx2 - bx1) * (1.0f / (float)WO);
        const float bin_h = (by2 - by1) * (1.0f / (float)HO);

        const float x1u = bx1 + (float)jj * bin_w;
        const float x1b = fminf(fmaxf(x1u, 0.0f), fW);
        const float x2b = fminf(fmaxf(x1u + bin_w, 0.0f), fW);
        const float y1u = by1 + (float)ii * bin_h;
        const float y1b = fminf(fmaxf(y1u, 0.0f), fH);
        const float y2b = fminf(fmaxf(y1u + bin_h, 0.0f), fH);
        const float vf = (roi_valid && (y2b > y1b) && (x2b > x1b)) ? 1.0f : 0.0f;

        int xl[2], xh[2], yl[2], yh[2];
#pragma unroll
        for (int s = 0; s < 2; ++s) {
            const float px = x1b + ((float)s + 0.5f) * (bin_w * 0.5f);
            int l = (int)floorf(px);
            l = min(max(l, 0), W_ - 1);
            const int h = min(l + 1, W_ - 1);
            xl[s] = l; xh[s] = h;
            wts[tid][0 + s] = vf * (px - (float)l);      // wxh[s]
            wts[tid][2 + s] = vf * ((float)h - px);      // wxl[s]

            const float py = y1b + ((float)s + 0.5f) * (bin_h * 0.5f);
            int t = (int)floorf(py);
            t = min(max(t, 0), H_ - 1);
            const int u = min(t + 1, H_ - 1);
            yl[s] = t; yh[s] = u;
            wts[tid][4 + s] = py - (float)t;             // wyb[s]
            wts[tid][6 + s] = (float)u - py;             // wyt[s]
        }
#pragma unroll
        for (int sy = 0; sy < 2; ++sy) {
#pragma unroll
            for (int sx = 0; sx < 2; ++sx) {
                const int s = sy * 2 + sx;
                const unsigned tl = (unsigned)(yl[sy] * W_ + xl[sx]);
                const unsigned tr = (unsigned)(yl[sy] * W_ + xh[sx]);
                const unsigned bl = (unsigned)(yh[sy] * W_ + xl[sx]);
                const unsigned br = (unsigned)(yh[sy] * W_ + xh[sx]);
                offs[tid][s * 2 + 0] = tl | (tr << 16);
                offs[tid][s * 2 + 1] = bl | (br << 16);
            }
        }
    }
    __syncthreads();

    // ---- Phase 2: half-waves = bins, cols = 4-channel groups ----
    int b = (int)rois[n * 5];
    b = min(max(b, 0), B_ - 1);
    const float4* pb = (const float4*)(ft + (size_t)b * HW * C_) + half * COLS + col;

    for (int i0 = wave * 2; i0 < NBIN; i0 += 8) {
        const int bin = i0 + sub;                        // per half-wave
        const int bc  = min(bin, NBIN - 1);              // clamp tail
        const float4 wa = *(const float4*)wts[bc];       // wxh0,wxh1,wxl0,wxl1
        const float4 wb = *(const float4*)(wts[bc] + 4); // wyb0,wyb1,wyt0,wyt1
        const uint4  oa = *(const uint4*)&offs[bc][0];   // samples 0,1
        const uint4  ob = *(const uint4*)&offs[bc][4];   // samples 2,3

        auto samp = [&](unsigned ptop, unsigned pbot,
                        float wxh, float wxl, float wyb, float wyt) -> float4 {
            const int tl = (int)(ptop & 0xffffu) << 6;   // hw * 64 float4s
            const int tr = (int)(ptop >> 16) << 6;
            const int bl = (int)(pbot & 0xffffu) << 6;
            const int br = (int)(pbot >> 16) << 6;
            const float4 v_tl = pb[tl], v_tr = pb[tr];
            const float4 v_bl = pb[bl], v_br = pb[br];
            float4 o;
            o.x = wyb * (wxh * v_br.x + wxl * v_bl.x) + wyt * (wxh * v_tr.x + wxl * v_tl.x);
            o.y = wyb * (wxh * v_br.y + wxl * v_bl.y) + wyt * (wxh * v_tr.y + wxl * v_tl.y);
            o.z = wyb * (wxh * v_br.z + wxl * v_bl.z) + wyt * (wxh * v_tr.z + wxl * v_tl.z);
            o.w = wyb * (wxh * v_br.w + wxl * v_bl.w) + wyt * (wxh * v_tr.w + wxl * v_tl.w);
            return o;
        };

        const float4 s0 = samp(oa.x, oa.y, wa.x, wa.z, wb.x, wb.z); // sy0,sx0
        const float4 s1 = samp(oa.z, oa.w, wa.y, wa.w, wb.x, wb.z); // sy0,sx1
        const float4 s2 = samp(ob.x, ob.y, wa.x, wa.z, wb.y, wb.w); // sy1,sx0
        const float4 s3 = samp(ob.z, ob.w, wa.y, wa.w, wb.y, wb.w); // sy1,sx1
        float4 m;
        m.x = fmaxf(fmaxf(s0.x, s1.x), fmaxf(s2.x, s3.x));
        m.y = fmaxf(fmaxf(s0.y, s1.y), fmaxf(s2.y, s3.y));
        m.z = fmaxf(fmaxf(s0.z, s1.z), fmaxf(s2.z, s3.z));
        m.w = fmaxf(fmaxf(s0.w, s1.w), fmaxf(s2.w, s3.w));

        if (bin < NBIN)
            *(float4*)&stage[bin * LDs + 4 * col] = m;   // aligned b128
    }
    __syncthreads();

    // ---- Phase 3: one contiguous 25088B span per block ----
    float* outn = out + (size_t)n * OUT_PER_ROI + half * (CPB * NBIN);
    for (int k = tid; k < CPB * NBIN; k += 256) {
        const int ch = k / NBIN;                         // magic mul
        const int bi = k - ch * NBIN;
        outn[k] = stage[bi * LDs + ch];
    }
}

} // namespace

extern "C" void kernel_launch(void* const* d_in, const int* in_sizes, int n_in,
                              void* d_out, int out_size, void* d_ws, size_t ws_size,
                              hipStream_t stream)
{
    const float* feats = (const float*)d_in[0];
    const float* rois  = (const float*)d_in[1];
    float* out = (float*)d_out;
    const int N = in_sizes[1] / 5;                    // 1024
    float* ft = (float*)d_ws;                         // 10.24 MB

    hipLaunchKernelGGL(transpose_tiled, dim3(B_ * 4 * 40), dim3(256), 0, stream,
                       feats, ft);
    hipLaunchKernelGGL(roialign_main, dim3(N, 2), dim3(256), 0, stream,
                       ft, rois, out);
}